// Round 1
// baseline (924.792 us; speedup 1.0000x reference)
//
#include <hip/hip_runtime.h>

// R9 = occupancy push: 2 samples/block, grid = B/2 = 1024 blocks.
// R8 (4 samples/block) was grid-limited to 2 blocks/CU (Occupancy 21%,
// MfmaUtil 22%, VALUBusy 43%, HBM idle -> latency-bound, ~70% stall).
//  - zimg: 18 n-rows (2 samples x 9 pos), 4 buffers = 19.6 KB. Reads for
//    n>=18 clamp to a valid row; results discarded by zv mask.
//  - z2 spike buffer: u8 (spikes {0,1} exact), overlaid on the init-only
//    s_x/w1/b1 region. Total LDS ~24.5 KB -> LDS allows 6 blocks/CU.
//  - __launch_bounds__(256,4) caps VGPR at 128 -> 16 waves/CU = 4 blocks.
//  - fc on waves 2,3 (least LIF1 work: wave2 has 28 rows, wave3 none).
//  - GEMM: 2 n-tiles x 3 i8 levels = 6 MFMA chains (24 acc VGPRs).
// Numerics identical to R8: 3-level nested i8 (~fp32-grade), exact i32 acc.

#define NSTEPS 100
#define NCHUNK 50
#define IMSTRIDE 272
#define NROW 18
#define ZIMG (NROW * IMSTRIDE)     // 4896 B per buffer; 4 buffers
#define Z2SLOT 1224                // u8 z2 per t-slot: 2 samples x 9 pos x 68

typedef __attribute__((ext_vector_type(4))) int i32x4;

// conv1 + 2x2 maxpool for one spike-row (sample, ic, y): 6 outputs
__device__ __forceinline__ void conv1_row(const float* __restrict__ xs,
                                          const float* __restrict__ w1s,
                                          float b1v, int y, float* cur) {
    float cr[2][12];
    #pragma unroll
    for (int rr = 0; rr < 2; ++rr) {
        const int cy = 2 * y + rr;
        #pragma unroll
        for (int cx = 0; cx < 12; ++cx) {
            float a = 0.f;
            #pragma unroll
            for (int ky = 0; ky < 4; ++ky)
            #pragma unroll
            for (int kx = 0; kx < 4; ++kx)
                a = fmaf(xs[(cy + ky) * 16 + cx + kx], w1s[ky * 4 + kx], a);
            cr[rr][cx] = a + b1v;
        }
    }
    #pragma unroll
    for (int px = 0; px < 6; ++px)
        cur[px] = fmaxf(fmaxf(cr[0][2 * px], cr[0][2 * px + 1]),
                        fmaxf(cr[1][2 * px], cr[1][2 * px + 1]));
}

// LIF1 step for one spike-row + sigma-permuted i8 scatter.
// pb = zimg_buffer_base + (9*sl + 3*y)*IMSTRIDE + 16*ic
__device__ __forceinline__ void lif1_row(float* v1, float* i1, const float* cur,
                                         unsigned char* pb, int ic, int y) {
    unsigned zb[6];
    #pragma unroll
    for (int xx = 0; xx < 6; ++xx) {
        const float vd = v1[xx] + 0.1f * (i1[xx] - v1[xx]);
        i1[xx] = i1[xx] * 0.8f + cur[xx];
        const bool sp = vd > 1.0f;
        v1[xx] = sp ? 0.0f : vd;
        zb[xx] = sp ? 1u : 0u;
    }
    const unsigned q0 = zb[0] | (zb[1] << 8) | (zb[2] << 16) | (zb[3] << 24);
    const unsigned q1 = zb[1] | (zb[2] << 8) | (zb[3] << 16) | (zb[4] << 24);
    const unsigned q2 = zb[2] | (zb[3] << 8) | (zb[4] << 16) | (zb[5] << 24);
    #pragma unroll
    for (int ky = 0; ky < 4; ++ky) {
        const int py = y - ky;
        if (0 <= py && py <= 2) {
            unsigned char* b = pb - ky * (3 * IMSTRIDE) + 4 * ((ky + ic) & 3);
            *(unsigned*)(b)                = q0;   // px = 0
            *(unsigned*)(b + IMSTRIDE)     = q1;   // px = 1
            *(unsigned*)(b + 2 * IMSTRIDE) = q2;   // px = 2
        }
    }
}

__global__ __launch_bounds__(256, 4)
void snn_kernel(const float* __restrict__ x,
                const float* __restrict__ w1,
                const float* __restrict__ b1,
                const float* __restrict__ w2,
                const float* __restrict__ b2,
                const float* __restrict__ wf,
                const float* __restrict__ bf,
                float* __restrict__ out, int B)
{
    __shared__ __align__(16) unsigned char s_im[4 * ZIMG];      // 19584 B
    __shared__ __align__(16) unsigned char s_ovl[4 * Z2SLOT];   // 4896 B

    // overlay: s_x/w1/b1 are only live before the first chunk barrier;
    // z2 slots are first written after it.
    float* const s_xf = (float*)s_ovl;                 // 2*256*4 = 2048 B
    float* const s_w1 = (float*)(s_ovl + 2048);        // 832 B
    float* const s_b1 = (float*)(s_ovl + 2880);        // 52 B
    unsigned char* const s_z2 = s_ovl;

    const int tid  = threadIdx.x;
    const int wave = tid >> 6, lane = tid & 63;
    const int quad = lane >> 4, col = lane & 15;

    // ---- stage x / w1 / b1; zero all 4 zimg buffers ----
    if (wave < 2)
        ((float4*)(s_xf + wave * 256))[lane] =
            ((const float4*)(x + (size_t)(blockIdx.x * 2 + wave) * 256))[lane];
    if (tid < 208) s_w1[tid] = w1[tid];
    if (tid < 13)  s_b1[tid] = b1[tid];
    for (int i = tid; i < 4 * ZIMG / 16; i += 256)
        ((uint4*)s_im)[i] = make_uint4(0, 0, 0, 0);
    __syncthreads();

    // ---- LIF1 row ownership: 156 rows = 2 samples * 13 ic * 6 y ----
    const bool rowv = tid < 156;
    int sA = 0, icA = 0, yA = 0;
    if (rowv) { sA = tid / 78; int r = tid - 78 * sA; icA = r / 6; yA = r - 6 * icA; }

    float cur1a[6], v1a[6], i1a[6];
    if (rowv) conv1_row(s_xf + sA * 256, s_w1 + icA * 16, s_b1[icA], yA, cur1a);
    #pragma unroll
    for (int j = 0; j < 6; ++j) { v1a[j] = 0.f; i1a[j] = 0.f; }
    const int pbOffA = (9 * sA + 3 * yA) * IMSTRIDE + 16 * icA;

    // ---- A-fragments: per-row 3-level i8 split of w2 (sigma-permuted K) ----
    i32x4 A1[4], A2[4], A3[4];
    float Mrow;
    {
        const float* wrow = w2 + (size_t)(wave * 16 + col) * 208;
        float M = 1e-20f;
        for (int k = 0; k < 208; ++k) M = fmaxf(M, fabsf(wrow[k]));
        Mrow = M;
        const float inv = 127.0f / M;
        const float q1s = M * (1.0f / 127.0f);
        const float q2s = M * (1.0f / (127.0f * 127.0f));
        #pragma unroll
        for (int kt = 0; kt < 4; ++kt) {
            i32x4 w1v = {0, 0, 0, 0}, w2v = {0, 0, 0, 0}, w3v = {0, 0, 0, 0};
            #pragma unroll
            for (int j = 0; j < 16; ++j) {
                const int kp = kt * 64 + quad * 16 + j;
                const int W = kp >> 2, kx = kp & 3;
                const int ic = W >> 2, ky = ((W & 3) - ic) & 3;
                const float w = (ic < 13) ? wrow[ic * 16 + ky * 4 + kx] : 0.f;
                const float b1f = rintf(w * inv);
                const float r1  = fmaf(b1f, -q1s, w);
                const float b2f = rintf(r1 * inv * 127.0f);
                const float r2  = fmaf(b2f, -q2s, r1);
                const float b3f = rintf(r2 * inv * 127.0f * 127.0f);
                const int wi = j >> 2, sh = (j & 3) * 8;
                w1v[wi] |= ((int)b1f & 0xFF) << sh;
                w2v[wi] |= ((int)b2f & 0xFF) << sh;
                w3v[wi] |= ((int)b3f & 0xFF) << sh;
            }
            A1[kt] = w1v; A2[kt] = w2v; A3[kt] = w3v;
        }
    }
    float sc1[4], sc2[4], sc3[4];
    #pragma unroll
    for (int r = 0; r < 4; ++r) {
        const float Mr = __shfl(Mrow, quad * 4 + r);
        sc1[r] = Mr * (1.0f / 127.0f);
        sc2[r] = Mr * (1.0f / (127.0f * 127.0f));
        sc3[r] = Mr * (1.0f / (127.0f * 127.0f * 127.0f));
    }

    // ---- static per-lane: fc weights, b2, B-frag / z2 offsets ----
    float wf0[9], wf1[9];
    #pragma unroll
    for (int q = 0; q < 9; ++q) {
        wf0[q] = wf[lane * 9 + q];          // fc reads z2[q*68 + lane] (oc=lane)
        wf1[q] = wf[576 + lane * 9 + q];
    }
    const float bfv0 = bf[0], bfv1 = bf[1];
    float b2r[4];
    #pragma unroll
    for (int r = 0; r < 4; ++r) b2r[r] = b2[wave * 16 + quad * 4 + r];

    int bpo[2];        // byte offset of B-frag within a zimg buffer
    int zwo[2];        // byte offset of z2 write within a t-slot
    bool zv[2];
    #pragma unroll
    for (int nt = 0; nt < 2; ++nt) {
        const int n = nt * 16 + col;
        const int nc = (n < 18) ? n : (n - 14);   // clamp: row stays valid
        bpo[nt] = nc * IMSTRIDE + quad * 16;
        zv[nt] = (n < 18);
        const int slz = nc / 9, pos = nc - 9 * slz;
        zwo[nt] = slz * 612 + pos * 68 + wave * 16 + quad * 4;
    }

    float v2[8], i2[8];
    #pragma unroll
    for (int p = 0; p < 8; ++p) { v2[p] = 0.f; i2[p] = 0.f; }
    float v3a = 0.f, i3a = 0.f, v3b = 0.f, i3b = 0.f, sum0 = 0.f, sum1 = 0.f;

    const int sGf = blockIdx.x * 2 + (wave - 2);   // valid for waves 2,3
    float* outv = out + (size_t)2 * B;

    // One fc + LIF3 step from a z2 t-slot base (u8), storing v3_seq[tp].
    auto fc_step = [&](const unsigned char* zs, int tp) {
        float p0 = 0.f, p1 = 0.f;
        #pragma unroll
        for (int q = 0; q < 9; ++q) {
            const float z = (float)zs[q * 68 + lane];
            p0 = fmaf(z, wf0[q], p0);
            p1 = fmaf(z, wf1[q], p1);
        }
        #pragma unroll
        for (int off = 32; off > 0; off >>= 1) {
            p0 += __shfl_xor(p0, off);
            p1 += __shfl_xor(p1, off);
        }
        const float c3a = p0 + bfv0, c3b = p1 + bfv1;
        const float vd0 = v3a + 0.1f * (i3a - v3a);
        const float vd1 = v3b + 0.1f * (i3b - v3b);
        i3a = i3a * 0.8f + c3a;
        i3b = i3b * 0.8f + c3b;
        const bool q0 = vd0 > 1.0f, q1 = vd1 > 1.0f;
        v3a = q0 ? 0.0f : vd0;
        v3b = q1 ? 0.0f : vd1;
        sum0 += q0 ? 1.0f : 0.0f;
        sum1 += q1 ? 1.0f : 0.0f;
        if (lane == 0)
            *(float2*)(outv + (size_t)tp * 2 * B + 2 * sGf) = make_float2(v3a, v3b);
    };

    // One chunk (2 timesteps), compile-time parity P at call sites.
    auto chunk = [&](int ch, int P) {
        // ---- Phase A: two LIF1 steps into zimg buffers 2P, 2P+1 ----
        unsigned char* zb0 = s_im + (2 * P) * ZIMG;
        unsigned char* zb1 = s_im + (2 * P + 1) * ZIMG;
        if (rowv) {
            lif1_row(v1a, i1a, cur1a, zb0 + pbOffA, icA, yA);
            lif1_row(v1a, i1a, cur1a, zb1 + pbOffA, icA, yA);
        }
        __syncthreads();                 // the only barrier per 2 steps

        // ---- deferred fc (waves 2,3): both steps of chunk ch-1 ----
        if (ch && wave >= 2) {
            const unsigned char* zp =
                s_z2 + ((P ^ 1) * 2) * Z2SLOT + (wave - 2) * 612;
            fc_step(zp, 2 * ch - 2);
            fc_step(zp + Z2SLOT, 2 * ch - 1);
        }

        // ---- GEMM + LIF2: two serial 6-chain passes ----
        #pragma unroll
        for (int tl = 0; tl < 2; ++tl) {
            const unsigned char* zbuf = s_im + (2 * P + tl) * ZIMG;
            i32x4 c1a = {0,0,0,0}, c1b = c1a;
            i32x4 c2a = c1a, c2b = c1a;
            i32x4 c3a_ = c1a, c3b_ = c1a;
            #pragma unroll
            for (int kt = 0; kt < 4; ++kt) {
                const i32x4 B0 = *(const i32x4*)(zbuf + bpo[0] + kt * 64);
                const i32x4 B1 = *(const i32x4*)(zbuf + bpo[1] + kt * 64);
                c1a = __builtin_amdgcn_mfma_i32_16x16x64_i8(A1[kt], B0, c1a, 0, 0, 0);
                c1b = __builtin_amdgcn_mfma_i32_16x16x64_i8(A1[kt], B1, c1b, 0, 0, 0);
                c2a = __builtin_amdgcn_mfma_i32_16x16x64_i8(A2[kt], B0, c2a, 0, 0, 0);
                c2b = __builtin_amdgcn_mfma_i32_16x16x64_i8(A2[kt], B1, c2b, 0, 0, 0);
                c3a_ = __builtin_amdgcn_mfma_i32_16x16x64_i8(A3[kt], B0, c3a_, 0, 0, 0);
                c3b_ = __builtin_amdgcn_mfma_i32_16x16x64_i8(A3[kt], B1, c3b_, 0, 0, 0);
            }

            const i32x4 L1[2] = {c1a, c1b};
            const i32x4 L2[2] = {c2a, c2b};
            const i32x4 L3[2] = {c3a_, c3b_};
            unsigned char* z2b = s_z2 + (2 * P + tl) * Z2SLOT;
            #pragma unroll
            for (int nt = 0; nt < 2; ++nt) {
                unsigned zby[4];
                #pragma unroll
                for (int r = 0; r < 4; ++r) {
                    const int p = nt * 4 + r;
                    const float cur2 =
                        fmaf(sc1[r], (float)L1[nt][r],
                        fmaf(sc2[r], (float)L2[nt][r],
                        fmaf(sc3[r], (float)L3[nt][r], b2r[r])));
                    const float vd = v2[p] + 0.1f * (i2[p] - v2[p]);
                    i2[p] = i2[p] * 0.8f + cur2;
                    const bool sp = vd > 1.0f;
                    v2[p] = sp ? 0.0f : vd;
                    zby[r] = sp ? 1u : 0u;
                }
                if (zv[nt])
                    *(unsigned*)(z2b + zwo[nt]) =
                        zby[0] | (zby[1] << 8) | (zby[2] << 16) | (zby[3] << 24);
            }
        }
    };

    #pragma unroll 1
    for (int cc = 0; cc < NCHUNK; cc += 2) {
        chunk(cc, 0);
        chunk(cc + 1, 1);
    }

    __syncthreads();
    if (wave >= 2) {   // final chunk (ch=49, P=1) fc: slots 2,3
        const unsigned char* zp = s_z2 + 2 * Z2SLOT + (wave - 2) * 612;
        fc_step(zp, NSTEPS - 2);
        fc_step(zp + Z2SLOT, NSTEPS - 1);
        if (lane == 0)
            *(float2*)(out + (size_t)2 * sGf) = make_float2(sum0, sum1);
    }
}

extern "C" void kernel_launch(void* const* d_in, const int* in_sizes, int n_in,
                              void* d_out, int out_size, void* d_ws, size_t ws_size,
                              hipStream_t stream)
{
    const float* x  = (const float*)d_in[0];
    const float* w1 = (const float*)d_in[1];
    const float* b1 = (const float*)d_in[2];
    const float* w2 = (const float*)d_in[3];
    const float* b2 = (const float*)d_in[4];
    const float* wf = (const float*)d_in[5];
    const float* bf = (const float*)d_in[6];
    float* out = (float*)d_out;

    const int B = in_sizes[0] / 256;     // x is [B,1,16,16]
    const int grid = B / 2;              // 2 samples per block

    hipLaunchKernelGGL(snn_kernel, dim3(grid), dim3(256), 0, stream,
                       x, w1, b1, w2, b2, wf, bf, out, B);
}

// Round 2
// 345.274 us; speedup vs baseline: 2.6784x; 2.6784x over previous
//
#include <hip/hip_runtime.h>

// R10 = R9 structure with the spill fixed.
// R9 ((256,4) bound) forced VGPR=64 -> massive scratch spills (FETCH 1.19 GB,
// WRITE 374 MB, 925 us). But it PROVED the occupancy theory: 47% occupancy =
// 4 blocks/CU resident with 24.5 KB LDS. R10 keeps the 2-sample/block,
// grid=B/2 structure and relaxes to __launch_bounds__(256,2) (R8's bound,
// which compiled to exactly 128 VGPR spill-free with MORE state than R9).
// At <=128 VGPR the HW still fits 4 waves/SIMD = 4 blocks/CU.
//  - zimg: 18 n-rows (2 samples x 9 pos), 4 buffers = 19.6 KB. Reads for
//    n>=18 clamp to a valid row; results discarded by zv mask.
//  - z2 spike buffer: u8 (spikes {0,1} exact), overlaid on the init-only
//    s_x/w1/b1 region. Total LDS ~24.5 KB.
//  - fc on waves 2,3 (least LIF1 work: wave2 has 28 rows, wave3 none).
//  - GEMM: 2 n-tiles x 3 i8 levels = 6 MFMA chains (24 acc VGPRs).
// Numerics identical to R8: 3-level nested i8 (~fp32-grade), exact i32 acc.

#define NSTEPS 100
#define NCHUNK 50
#define IMSTRIDE 272
#define NROW 18
#define ZIMG (NROW * IMSTRIDE)     // 4896 B per buffer; 4 buffers
#define Z2SLOT 1224                // u8 z2 per t-slot: 2 samples x 9 pos x 68

typedef __attribute__((ext_vector_type(4))) int i32x4;

// conv1 + 2x2 maxpool for one spike-row (sample, ic, y): 6 outputs
__device__ __forceinline__ void conv1_row(const float* __restrict__ xs,
                                          const float* __restrict__ w1s,
                                          float b1v, int y, float* cur) {
    float cr[2][12];
    #pragma unroll
    for (int rr = 0; rr < 2; ++rr) {
        const int cy = 2 * y + rr;
        #pragma unroll
        for (int cx = 0; cx < 12; ++cx) {
            float a = 0.f;
            #pragma unroll
            for (int ky = 0; ky < 4; ++ky)
            #pragma unroll
            for (int kx = 0; kx < 4; ++kx)
                a = fmaf(xs[(cy + ky) * 16 + cx + kx], w1s[ky * 4 + kx], a);
            cr[rr][cx] = a + b1v;
        }
    }
    #pragma unroll
    for (int px = 0; px < 6; ++px)
        cur[px] = fmaxf(fmaxf(cr[0][2 * px], cr[0][2 * px + 1]),
                        fmaxf(cr[1][2 * px], cr[1][2 * px + 1]));
}

// LIF1 step for one spike-row + sigma-permuted i8 scatter.
// pb = zimg_buffer_base + (9*sl + 3*y)*IMSTRIDE + 16*ic
__device__ __forceinline__ void lif1_row(float* v1, float* i1, const float* cur,
                                         unsigned char* pb, int ic, int y) {
    unsigned zb[6];
    #pragma unroll
    for (int xx = 0; xx < 6; ++xx) {
        const float vd = v1[xx] + 0.1f * (i1[xx] - v1[xx]);
        i1[xx] = i1[xx] * 0.8f + cur[xx];
        const bool sp = vd > 1.0f;
        v1[xx] = sp ? 0.0f : vd;
        zb[xx] = sp ? 1u : 0u;
    }
    const unsigned q0 = zb[0] | (zb[1] << 8) | (zb[2] << 16) | (zb[3] << 24);
    const unsigned q1 = zb[1] | (zb[2] << 8) | (zb[3] << 16) | (zb[4] << 24);
    const unsigned q2 = zb[2] | (zb[3] << 8) | (zb[4] << 16) | (zb[5] << 24);
    #pragma unroll
    for (int ky = 0; ky < 4; ++ky) {
        const int py = y - ky;
        if (0 <= py && py <= 2) {
            unsigned char* b = pb - ky * (3 * IMSTRIDE) + 4 * ((ky + ic) & 3);
            *(unsigned*)(b)                = q0;   // px = 0
            *(unsigned*)(b + IMSTRIDE)     = q1;   // px = 1
            *(unsigned*)(b + 2 * IMSTRIDE) = q2;   // px = 2
        }
    }
}

__global__ __launch_bounds__(256, 2)
void snn_kernel(const float* __restrict__ x,
                const float* __restrict__ w1,
                const float* __restrict__ b1,
                const float* __restrict__ w2,
                const float* __restrict__ b2,
                const float* __restrict__ wf,
                const float* __restrict__ bf,
                float* __restrict__ out, int B)
{
    __shared__ __align__(16) unsigned char s_im[4 * ZIMG];      // 19584 B
    __shared__ __align__(16) unsigned char s_ovl[4 * Z2SLOT];   // 4896 B

    // overlay: s_x/w1/b1 are only live before the first chunk barrier;
    // z2 slots are first written after it.
    float* const s_xf = (float*)s_ovl;                 // 2*256*4 = 2048 B
    float* const s_w1 = (float*)(s_ovl + 2048);        // 832 B
    float* const s_b1 = (float*)(s_ovl + 2880);        // 52 B
    unsigned char* const s_z2 = s_ovl;

    const int tid  = threadIdx.x;
    const int wave = tid >> 6, lane = tid & 63;
    const int quad = lane >> 4, col = lane & 15;

    // ---- stage x / w1 / b1; zero all 4 zimg buffers ----
    if (wave < 2)
        ((float4*)(s_xf + wave * 256))[lane] =
            ((const float4*)(x + (size_t)(blockIdx.x * 2 + wave) * 256))[lane];
    if (tid < 208) s_w1[tid] = w1[tid];
    if (tid < 13)  s_b1[tid] = b1[tid];
    for (int i = tid; i < 4 * ZIMG / 16; i += 256)
        ((uint4*)s_im)[i] = make_uint4(0, 0, 0, 0);
    __syncthreads();

    // ---- LIF1 row ownership: 156 rows = 2 samples * 13 ic * 6 y ----
    const bool rowv = tid < 156;
    int sA = 0, icA = 0, yA = 0;
    if (rowv) { sA = tid / 78; int r = tid - 78 * sA; icA = r / 6; yA = r - 6 * icA; }

    float cur1a[6], v1a[6], i1a[6];
    if (rowv) conv1_row(s_xf + sA * 256, s_w1 + icA * 16, s_b1[icA], yA, cur1a);
    #pragma unroll
    for (int j = 0; j < 6; ++j) { v1a[j] = 0.f; i1a[j] = 0.f; }
    const int pbOffA = (9 * sA + 3 * yA) * IMSTRIDE + 16 * icA;

    // ---- A-fragments: per-row 3-level i8 split of w2 (sigma-permuted K) ----
    i32x4 A1[4], A2[4], A3[4];
    float Mrow;
    {
        const float* wrow = w2 + (size_t)(wave * 16 + col) * 208;
        float M = 1e-20f;
        for (int k = 0; k < 208; ++k) M = fmaxf(M, fabsf(wrow[k]));
        Mrow = M;
        const float inv = 127.0f / M;
        const float q1s = M * (1.0f / 127.0f);
        const float q2s = M * (1.0f / (127.0f * 127.0f));
        #pragma unroll
        for (int kt = 0; kt < 4; ++kt) {
            i32x4 w1v = {0, 0, 0, 0}, w2v = {0, 0, 0, 0}, w3v = {0, 0, 0, 0};
            #pragma unroll
            for (int j = 0; j < 16; ++j) {
                const int kp = kt * 64 + quad * 16 + j;
                const int W = kp >> 2, kx = kp & 3;
                const int ic = W >> 2, ky = ((W & 3) - ic) & 3;
                const float w = (ic < 13) ? wrow[ic * 16 + ky * 4 + kx] : 0.f;
                const float b1f = rintf(w * inv);
                const float r1  = fmaf(b1f, -q1s, w);
                const float b2f = rintf(r1 * inv * 127.0f);
                const float r2  = fmaf(b2f, -q2s, r1);
                const float b3f = rintf(r2 * inv * 127.0f * 127.0f);
                const int wi = j >> 2, sh = (j & 3) * 8;
                w1v[wi] |= ((int)b1f & 0xFF) << sh;
                w2v[wi] |= ((int)b2f & 0xFF) << sh;
                w3v[wi] |= ((int)b3f & 0xFF) << sh;
            }
            A1[kt] = w1v; A2[kt] = w2v; A3[kt] = w3v;
        }
    }
    float sc1[4], sc2[4], sc3[4];
    #pragma unroll
    for (int r = 0; r < 4; ++r) {
        const float Mr = __shfl(Mrow, quad * 4 + r);
        sc1[r] = Mr * (1.0f / 127.0f);
        sc2[r] = Mr * (1.0f / (127.0f * 127.0f));
        sc3[r] = Mr * (1.0f / (127.0f * 127.0f * 127.0f));
    }

    // ---- static per-lane: fc weights, b2, B-frag / z2 offsets ----
    float wf0[9], wf1[9];
    #pragma unroll
    for (int q = 0; q < 9; ++q) {
        wf0[q] = wf[lane * 9 + q];          // fc reads z2[q*68 + lane] (oc=lane)
        wf1[q] = wf[576 + lane * 9 + q];
    }
    const float bfv0 = bf[0], bfv1 = bf[1];
    float b2r[4];
    #pragma unroll
    for (int r = 0; r < 4; ++r) b2r[r] = b2[wave * 16 + quad * 4 + r];

    int bpo[2];        // byte offset of B-frag within a zimg buffer
    int zwo[2];        // byte offset of z2 write within a t-slot
    bool zv[2];
    #pragma unroll
    for (int nt = 0; nt < 2; ++nt) {
        const int n = nt * 16 + col;
        const int nc = (n < 18) ? n : (n - 14);   // clamp: row stays valid
        bpo[nt] = nc * IMSTRIDE + quad * 16;
        zv[nt] = (n < 18);
        const int slz = nc / 9, pos = nc - 9 * slz;
        zwo[nt] = slz * 612 + pos * 68 + wave * 16 + quad * 4;
    }

    float v2[8], i2[8];
    #pragma unroll
    for (int p = 0; p < 8; ++p) { v2[p] = 0.f; i2[p] = 0.f; }
    float v3a = 0.f, i3a = 0.f, v3b = 0.f, i3b = 0.f, sum0 = 0.f, sum1 = 0.f;

    const int sGf = blockIdx.x * 2 + (wave - 2);   // valid for waves 2,3
    float* outv = out + (size_t)2 * B;

    // One fc + LIF3 step from a z2 t-slot base (u8), storing v3_seq[tp].
    auto fc_step = [&](const unsigned char* zs, int tp) {
        float p0 = 0.f, p1 = 0.f;
        #pragma unroll
        for (int q = 0; q < 9; ++q) {
            const float z = (float)zs[q * 68 + lane];
            p0 = fmaf(z, wf0[q], p0);
            p1 = fmaf(z, wf1[q], p1);
        }
        #pragma unroll
        for (int off = 32; off > 0; off >>= 1) {
            p0 += __shfl_xor(p0, off);
            p1 += __shfl_xor(p1, off);
        }
        const float c3a = p0 + bfv0, c3b = p1 + bfv1;
        const float vd0 = v3a + 0.1f * (i3a - v3a);
        const float vd1 = v3b + 0.1f * (i3b - v3b);
        i3a = i3a * 0.8f + c3a;
        i3b = i3b * 0.8f + c3b;
        const bool q0 = vd0 > 1.0f, q1 = vd1 > 1.0f;
        v3a = q0 ? 0.0f : vd0;
        v3b = q1 ? 0.0f : vd1;
        sum0 += q0 ? 1.0f : 0.0f;
        sum1 += q1 ? 1.0f : 0.0f;
        if (lane == 0)
            *(float2*)(outv + (size_t)tp * 2 * B + 2 * sGf) = make_float2(v3a, v3b);
    };

    // One chunk (2 timesteps), compile-time parity P at call sites.
    auto chunk = [&](int ch, int P) {
        // ---- Phase A: two LIF1 steps into zimg buffers 2P, 2P+1 ----
        unsigned char* zb0 = s_im + (2 * P) * ZIMG;
        unsigned char* zb1 = s_im + (2 * P + 1) * ZIMG;
        if (rowv) {
            lif1_row(v1a, i1a, cur1a, zb0 + pbOffA, icA, yA);
            lif1_row(v1a, i1a, cur1a, zb1 + pbOffA, icA, yA);
        }
        __syncthreads();                 // the only barrier per 2 steps

        // ---- deferred fc (waves 2,3): both steps of chunk ch-1 ----
        if (ch && wave >= 2) {
            const unsigned char* zp =
                s_z2 + ((P ^ 1) * 2) * Z2SLOT + (wave - 2) * 612;
            fc_step(zp, 2 * ch - 2);
            fc_step(zp + Z2SLOT, 2 * ch - 1);
        }

        // ---- GEMM + LIF2: two serial 6-chain passes ----
        #pragma unroll
        for (int tl = 0; tl < 2; ++tl) {
            const unsigned char* zbuf = s_im + (2 * P + tl) * ZIMG;
            i32x4 c1a = {0,0,0,0}, c1b = c1a;
            i32x4 c2a = c1a, c2b = c1a;
            i32x4 c3a_ = c1a, c3b_ = c1a;
            #pragma unroll
            for (int kt = 0; kt < 4; ++kt) {
                const i32x4 B0 = *(const i32x4*)(zbuf + bpo[0] + kt * 64);
                const i32x4 B1 = *(const i32x4*)(zbuf + bpo[1] + kt * 64);
                c1a = __builtin_amdgcn_mfma_i32_16x16x64_i8(A1[kt], B0, c1a, 0, 0, 0);
                c1b = __builtin_amdgcn_mfma_i32_16x16x64_i8(A1[kt], B1, c1b, 0, 0, 0);
                c2a = __builtin_amdgcn_mfma_i32_16x16x64_i8(A2[kt], B0, c2a, 0, 0, 0);
                c2b = __builtin_amdgcn_mfma_i32_16x16x64_i8(A2[kt], B1, c2b, 0, 0, 0);
                c3a_ = __builtin_amdgcn_mfma_i32_16x16x64_i8(A3[kt], B0, c3a_, 0, 0, 0);
                c3b_ = __builtin_amdgcn_mfma_i32_16x16x64_i8(A3[kt], B1, c3b_, 0, 0, 0);
            }

            const i32x4 L1[2] = {c1a, c1b};
            const i32x4 L2[2] = {c2a, c2b};
            const i32x4 L3[2] = {c3a_, c3b_};
            unsigned char* z2b = s_z2 + (2 * P + tl) * Z2SLOT;
            #pragma unroll
            for (int nt = 0; nt < 2; ++nt) {
                unsigned zby[4];
                #pragma unroll
                for (int r = 0; r < 4; ++r) {
                    const int p = nt * 4 + r;
                    const float cur2 =
                        fmaf(sc1[r], (float)L1[nt][r],
                        fmaf(sc2[r], (float)L2[nt][r],
                        fmaf(sc3[r], (float)L3[nt][r], b2r[r])));
                    const float vd = v2[p] + 0.1f * (i2[p] - v2[p]);
                    i2[p] = i2[p] * 0.8f + cur2;
                    const bool sp = vd > 1.0f;
                    v2[p] = sp ? 0.0f : vd;
                    zby[r] = sp ? 1u : 0u;
                }
                if (zv[nt])
                    *(unsigned*)(z2b + zwo[nt]) =
                        zby[0] | (zby[1] << 8) | (zby[2] << 16) | (zby[3] << 24);
            }
        }
    };

    #pragma unroll 1
    for (int cc = 0; cc < NCHUNK; cc += 2) {
        chunk(cc, 0);
        chunk(cc + 1, 1);
    }

    __syncthreads();
    if (wave >= 2) {   // final chunk (ch=49, P=1) fc: slots 2,3
        const unsigned char* zp = s_z2 + 2 * Z2SLOT + (wave - 2) * 612;
        fc_step(zp, NSTEPS - 2);
        fc_step(zp + Z2SLOT, NSTEPS - 1);
        if (lane == 0)
            *(float2*)(out + (size_t)2 * sGf) = make_float2(sum0, sum1);
    }
}

extern "C" void kernel_launch(void* const* d_in, const int* in_sizes, int n_in,
                              void* d_out, int out_size, void* d_ws, size_t ws_size,
                              hipStream_t stream)
{
    const float* x  = (const float*)d_in[0];
    const float* w1 = (const float*)d_in[1];
    const float* b1 = (const float*)d_in[2];
    const float* w2 = (const float*)d_in[3];
    const float* b2 = (const float*)d_in[4];
    const float* wf = (const float*)d_in[5];
    const float* bf = (const float*)d_in[6];
    float* out = (float*)d_out;

    const int B = in_sizes[0] / 256;     // x is [B,1,16,16]
    const int grid = B / 2;              // 2 samples per block

    hipLaunchKernelGGL(snn_kernel, dim3(grid), dim3(256), 0, stream,
                       x, w1, b1, w2, b2, wf, bf, out, B);
}